// Round 4
// baseline (282.241 us; speedup 1.0000x reference)
//
#include <hip/hip_runtime.h>

typedef short s8v __attribute__((ext_vector_type(8)));
typedef float f4v __attribute__((ext_vector_type(4)));
typedef float f4 __attribute__((ext_vector_type(4)));

#define N_PIX 16384
#define NE    8192
#define EDIM  256
#define ZQ_ELEMS 4194304
#define MARGIN 4.5e-4f
#define NGRP 512           // 16 codes per pruning group

__device__ __forceinline__ float bf2f(unsigned short u) {
    union { unsigned int i; float f; } c; c.i = ((unsigned int)u) << 16; return c.f;
}
__device__ __forceinline__ unsigned short f2bf(float f) {
    unsigned int u = __float_as_uint(f);
    u = (u + 0x7fffu + ((u >> 16) & 1u)) >> 16;   // RNE
    return (unsigned short)u;
}
__device__ __forceinline__ unsigned short f2bf_down(float f) {  // round toward -inf
    unsigned int u = __float_as_uint(f);
    unsigned short b = (unsigned short)(u >> 16);
    if ((u & 0xFFFFu) && (u >> 31)) b += 1;
    return b;
}

// numpy pairwise_sum over 128 squared elements (exact replication: 8
// accumulators, fixed combine tree), f32 RN ops, no FMA contraction.
__device__ __forceinline__ float np_pw128sq(const float* a) {
    float r[8];
    #pragma unroll
    for (int j = 0; j < 8; ++j) r[j] = __fmul_rn(a[j], a[j]);
    for (int i = 8; i < 128; i += 8)
        #pragma unroll
        for (int j = 0; j < 8; ++j) r[j] = __fadd_rn(r[j], __fmul_rn(a[i + j], a[i + j]));
    return __fadd_rn(__fadd_rn(__fadd_rn(r[0], r[1]), __fadd_rn(r[2], r[3])),
                     __fadd_rn(__fadd_rn(r[4], r[5]), __fadd_rn(r[6], r[7])));
}

// K0: cb16 = bf16(cb); esum32[k] = np.sum(cb[k]*cb[k]) in exact np-f32
// pairwise semantics. WS-only writes.
__global__ __launch_bounds__(256) void vq_prep(const float* __restrict__ cb,
                                               unsigned short* __restrict__ cb16,
                                               float* __restrict__ esum32) {
    int t = threadIdx.x;
    int base = blockIdx.x * 64;
    const float* src = cb + (size_t)base * EDIM;
    unsigned short* dst = cb16 + (size_t)base * EDIM;
    for (int i = 0; i < 64; ++i) dst[i * EDIM + t] = f2bf(src[i * EDIM + t]);
    if (t < 64) {
        const float* a = cb + (size_t)(base + t) * EDIM;
        esum32[base + t] = __fadd_rn(np_pw128sq(a), np_pw128sq(a + 128));
    }
}

// K0b: z16[pixel][channel] = bf16(z) -- pixel-major transpose of z so
// phase1g can stage it with clean global_load_lds. LDS-transpose tile
// 64px x 64ch; reads and writes both coalesced; f2bf identical to what
// the old phase1 applied per element (bit-identical MFMA inputs).
__global__ __launch_bounds__(256) void vq_zprep(const float* __restrict__ z,
                                                unsigned short* __restrict__ z16) {
    __shared__ unsigned short zl[64 * 66];   // 66 stride: odd bank step
    int t = threadIdx.x;
    int p0 = (blockIdx.x >> 2) * 64;         // 64 | 1024, tile stays in one image
    int c0 = (blockIdx.x & 3) * 64;
    int b = p0 >> 10, hw0 = p0 & 1023;
    const float* src = z + (((size_t)b * 256 + c0) << 10) + hw0;
    #pragma unroll
    for (int i = 0; i < 16; ++i) {
        int idx = i * 256 + t;
        int ch = idx >> 6, px = idx & 63;    // lanes sweep px: coalesced f32 read
        zl[px * 66 + ch] = f2bf(src[((size_t)ch << 10) + px]);
    }
    __syncthreads();
    #pragma unroll
    for (int i = 0; i < 16; ++i) {
        int idx = i * 256 + t;
        int px = idx >> 6, ch = idx & 63;    // lanes sweep ch: coalesced u16 write
        z16[((size_t)(p0 + px)) * 256 + c0 + ch] = zl[px * 66 + ch];
    }
}

// K1: persistent-N 256x256-tile bf16 GEMM, 4-phase K-tile schedule.
// Each block owns 256 codes x 2048 pixels: 8 px-tiles x 4 K-tiles = 32
// linear K-tile iterations (vs 4 in round 3), so the pipeline reaches
// steady state and prologue/epilogue amortize 8x. Grid = 32 code-tiles x
// 8 px-groups = 256 blocks = 1/CU in ONE round. blockIdx = cm*8+pg: each
// XCD owns one px-group -> its 1MB B panel is L2-resident; A (4MB cb16)
// sweeps its L2. Staging is front-loaded: P1 stages next-tile A-k0,B-k0,
// P2 stages A-k1,B-k1, so the head gate vmcnt(4) and mid gate vmcnt(8)
// wait on loads issued a FULL K-tile (4 phases) earlier. Per-px-tile
// epilogue (reduce+store gmin, acc reset) is wave-local and uniform.
// LDS layout + involution swizzle identical to round 3 (verified):
// per operand-half [256 rows][4 chunks of 16B], physical chunk =
// q ^ ((row>>1)&3); stage source pre-swizzled, GLL dest linear.
// K order per output: kt,kh ascending 32-chunks -> gmin bit-identical.
__global__ __launch_bounds__(512, 2) void vq_phase1g(const unsigned short* __restrict__ cb16,
                                                     const unsigned short* __restrict__ z16,
                                                     unsigned short* __restrict__ gmin) {
    __shared__ unsigned short L[2][32768];   // [buf][A 16K u16 | B 16K u16] = 128 KB
    const int t = threadIdx.x;
    const int wave = t >> 6, lane = t & 63;
    const int q = lane >> 4, r = lane & 15;
    const int wr = wave >> 2, wc = wave & 3;      // 2 M-waves x 4 N-waves
    const int cm0 = ((int)blockIdx.x >> 3) * 256; // code tile (32 of them)
    const int pg  = (int)blockIdx.x & 7;          // px-group (8): one per XCD

    // Staging jobs: one half-step = 256 rows x 32 k of one operand = 16 KB
    // = 2 x 16B slots/thread. Physical slot pc=(row,cph) holds logical
    // chunk lc = cph ^ ((row>>1)&3)  (involution).
    const int pc0 = t, pc1 = t + 512;
    const int row0 = pc0 >> 2, row1 = pc1 >> 2;
    const int lc0 = (pc0 & 3) ^ ((row0 >> 1) & 3);
    const int lc1 = (pc1 & 3) ^ ((row1 >> 1) & 3);
    const int go0 = row0 * 256 + lc0 * 8;   // u16; + kh*32 + kt*64
    const int go1 = row1 * 256 + lc1 * 8;
    const int ld0 = pc0 * 8;                // u16 within half; + kh*8192
    const int ld1 = pc1 * 8;

    const unsigned short* gA = cb16 + (size_t)cm0 * 256;
    const unsigned short* gB0 = z16 + (size_t)pg * 2048 * 256;  // px-group base

    f4v acc[8][4];
    const f4v zz = {0.f, 0.f, 0.f, 0.f};
    #pragma unroll
    for (int mi = 0; mi < 8; ++mi)
        #pragma unroll
        for (int ni = 0; ni < 4; ++ni) acc[mi][ni] = zz;

    const int cxo = (q ^ ((r >> 1) & 3)) * 8;     // swizzled chunk offset (u16)

#define GLL(g, l) __builtin_amdgcn_global_load_lds( \
        (const __attribute__((address_space(1))) unsigned int*)(g), \
        (__attribute__((address_space(3))) unsigned int*)(l), 16, 0, 0)
#define STAGE(gbase, lbase, kh, gk) do { \
        GLL((gbase) + go0 + (kh) * 32 + (gk), (lbase) + (kh) * 8192 + ld0); \
        GLL((gbase) + go1 + (kh) * 32 + (gk), (lbase) + (kh) * 8192 + ld1); } while (0)

    // prologue: stage iteration 0 (px-tile 0, kt 0) into buf 0.
    // Order matters for the gate counts: A-k0, B-k0 (oldest 4), A-k1, B-k1.
    STAGE(gA, &L[0][0], 0, 0);
    STAGE(gB0, &L[0][16384], 0, 0);
    STAGE(gA, &L[0][0], 1, 0);
    STAGE(gB0, &L[0][16384], 1, 0);

    for (int it = 0; it < 32; ++it) {             // it = p*4 + kt, linear
        const int buf = it & 1;
        const unsigned short* Ab = &L[buf][0];
        const unsigned short* Bb = &L[buf][16384];
        unsigned short* An = &L[buf ^ 1][0];
        unsigned short* Bn = &L[buf ^ 1][16384];
        const int nit = it + 1;
        const bool st = nit < 32;
        const int gk = (nit & 3) * 64;            // next K-tile k-offset
        const unsigned short* gBn = gB0 + (size_t)(nit >> 2) * 256 * 256;

        // head gate: A-k0,B-k0 of this tile landed (issued P1 of it-1,
        // 4 phases ago); 4 younger (A-k1,B-k1) fly on.
        asm volatile("s_waitcnt vmcnt(4)" ::: "memory");
        __builtin_amdgcn_s_barrier();
        __builtin_amdgcn_sched_barrier(0);

        s8v Af[4], Bf[4];
        // ---- P1: kh0, mi 0-3; stage next-tile A-k0,B-k0 ----
        #pragma unroll
        for (int ni = 0; ni < 4; ++ni)
            Bf[ni] = *(const s8v*)&Bb[(wc * 64 + ni * 16 + r) * 32 + cxo];
        #pragma unroll
        for (int mi = 0; mi < 4; ++mi)
            Af[mi] = *(const s8v*)&Ab[(wr * 128 + mi * 16 + r) * 32 + cxo];
        if (st) { STAGE(gA, An, 0, gk); STAGE(gBn, Bn, 0, gk); }
        __builtin_amdgcn_s_barrier();
        __builtin_amdgcn_sched_barrier(0);
        __builtin_amdgcn_s_setprio(1);
        #pragma unroll
        for (int mi = 0; mi < 4; ++mi)
            #pragma unroll
            for (int ni = 0; ni < 4; ++ni)
                acc[mi][ni] = __builtin_amdgcn_mfma_f32_16x16x32_bf16(
                    Af[mi], Bf[ni], acc[mi][ni], 0, 0, 0);
        __builtin_amdgcn_s_setprio(0);
        __builtin_amdgcn_s_barrier();

        // ---- P2: kh0, mi 4-7 (B held); stage next-tile A-k1,B-k1 ----
        #pragma unroll
        for (int mi = 0; mi < 4; ++mi)
            Af[mi] = *(const s8v*)&Ab[(wr * 128 + (4 + mi) * 16 + r) * 32 + cxo];
        if (st) { STAGE(gA, An, 1, gk); STAGE(gBn, Bn, 1, gk); }
        __builtin_amdgcn_s_barrier();
        __builtin_amdgcn_sched_barrier(0);
        __builtin_amdgcn_s_setprio(1);
        #pragma unroll
        for (int mi = 0; mi < 4; ++mi)
            #pragma unroll
            for (int ni = 0; ni < 4; ++ni)
                acc[4 + mi][ni] = __builtin_amdgcn_mfma_f32_16x16x32_bf16(
                    Af[mi], Bf[ni], acc[4 + mi][ni], 0, 0, 0);
        __builtin_amdgcn_s_setprio(0);
        // mid gate: A-k1,B-k1 of this tile landed (issued P2 of it-1).
        // Outstanding <= 12 (4 maybe-live + 8 new); retire to 8.
        asm volatile("s_waitcnt vmcnt(8)" ::: "memory");
        __builtin_amdgcn_s_barrier();
        __builtin_amdgcn_sched_barrier(0);

        // ---- P3: kh1, mi 0-3 (no stage) ----
        #pragma unroll
        for (int ni = 0; ni < 4; ++ni)
            Bf[ni] = *(const s8v*)&Bb[8192 + (wc * 64 + ni * 16 + r) * 32 + cxo];
        #pragma unroll
        for (int mi = 0; mi < 4; ++mi)
            Af[mi] = *(const s8v*)&Ab[8192 + (wr * 128 + mi * 16 + r) * 32 + cxo];
        __builtin_amdgcn_s_barrier();
        __builtin_amdgcn_sched_barrier(0);
        __builtin_amdgcn_s_setprio(1);
        #pragma unroll
        for (int mi = 0; mi < 4; ++mi)
            #pragma unroll
            for (int ni = 0; ni < 4; ++ni)
                acc[mi][ni] = __builtin_amdgcn_mfma_f32_16x16x32_bf16(
                    Af[mi], Bf[ni], acc[mi][ni], 0, 0, 0);
        __builtin_amdgcn_s_setprio(0);
        __builtin_amdgcn_s_barrier();

        // ---- P4: kh1, mi 4-7 (no stage) ----
        #pragma unroll
        for (int mi = 0; mi < 4; ++mi)
            Af[mi] = *(const s8v*)&Ab[8192 + (wr * 128 + (4 + mi) * 16 + r) * 32 + cxo];
        __builtin_amdgcn_s_barrier();
        __builtin_amdgcn_sched_barrier(0);
        __builtin_amdgcn_s_setprio(1);
        #pragma unroll
        for (int mi = 0; mi < 4; ++mi)
            #pragma unroll
            for (int ni = 0; ni < 4; ++ni)
                acc[4 + mi][ni] = __builtin_amdgcn_mfma_f32_16x16x32_bf16(
                    Af[mi], Bf[ni], acc[4 + mi][ni], 0, 0, 0);
        __builtin_amdgcn_s_setprio(0);

        // px-tile boundary: emit this px-tile's group-maxes, reset acc.
        // Wave-local (own acc only), uniform branch -> no barrier needed.
        if ((it & 3) == 3) {
            const int pn0 = pg * 2048 + (it >> 2) * 256;
            #pragma unroll
            for (int mi = 0; mi < 8; ++mi) {
                int g = cm0 / 16 + wr * 8 + mi;
                #pragma unroll
                for (int ni = 0; ni < 4; ++ni) {
                    f4v a = acc[mi][ni];
                    float mx = fmaxf(fmaxf(a[0], a[1]), fmaxf(a[2], a[3]));
                    mx = fmaxf(mx, __shfl_xor(mx, 16));
                    mx = fmaxf(mx, __shfl_xor(mx, 32));
                    if (q == 0)
                        gmin[(size_t)g * N_PIX + pn0 + wc * 64 + ni * 16 + r] =
                            f2bf_down(-2.0f * mx);
                    acc[mi][ni] = zz;
                }
            }
        }
        // next head gate doubles as P4's closing barrier
    }
#undef STAGE
#undef GLL
}

// K1 (fallback, unchanged): used only if workspace can't hold z16.
__global__ __launch_bounds__(512, 2) void vq_phase1(const float* __restrict__ z,
                                                    const unsigned short* __restrict__ cb16,
                                                    unsigned short* __restrict__ gmin) {
    const int t = threadIdx.x;
    const int wave = t >> 6, lane = t & 63;
    const int col = lane & 15, q = lane >> 4;
    const int mb = (blockIdx.x >> 1) * 64;
    const int chalf = blockIdx.x & 1;

    s8v Z[4][8];
    #pragma unroll
    for (int pt = 0; pt < 4; ++pt) {
        int n = mb + pt * 16 + col;
        const float* zb = z + ((size_t)(n >> 10) << 18) + (size_t)(n & 1023);
        #pragma unroll
        for (int c0 = 0; c0 < 8; ++c0) {
            s8v a;
            #pragma unroll
            for (int j = 0; j < 8; ++j) {
                int c = c0 * 32 + q * 8 + j;
                a[j] = (short)f2bf(zb[(size_t)c << 10]);
            }
            Z[pt][c0] = a;
        }
    }

    const int kbase = chalf * 4096 + wave * 512;
    for (int it = 0; it < 16; ++it) {
        int n0 = kbase + it * 32;
        const unsigned short* bb = cb16 + (size_t)(n0 + col) * EDIM + q * 8;
        f4v zz = {0.f, 0.f, 0.f, 0.f};
        f4v acc[4][2];
        #pragma unroll
        for (int pt = 0; pt < 4; ++pt) { acc[pt][0] = zz; acc[pt][1] = zz; }
        #pragma unroll
        for (int c0 = 0; c0 < 8; ++c0) {
            s8v C0 = *(const s8v*)(bb + c0 * 32);
            s8v C1 = *(const s8v*)(bb + 16 * EDIM + c0 * 32);
            #pragma unroll
            for (int pt = 0; pt < 4; ++pt) {
                acc[pt][0] = __builtin_amdgcn_mfma_f32_16x16x32_bf16(C0, Z[pt][c0], acc[pt][0], 0, 0, 0);
                acc[pt][1] = __builtin_amdgcn_mfma_f32_16x16x32_bf16(C1, Z[pt][c0], acc[pt][1], 0, 0, 0);
            }
        }
        int gbase = chalf * 256 + wave * 32 + it * 2;
        #pragma unroll
        for (int pt = 0; pt < 4; ++pt) {
            #pragma unroll
            for (int s = 0; s < 2; ++s) {
                f4v a = acc[pt][s];
                float mx = fmaxf(fmaxf(a[0], a[1]), fmaxf(a[2], a[3]));
                mx = fmaxf(mx, __shfl_xor(mx, 16));
                mx = fmaxf(mx, __shfl_xor(mx, 32));
                if (q == 0)
                    gmin[(size_t)(gbase + s) * N_PIX + mb + pt * 16 + col] =
                        f2bf_down(-2.0f * mx);
            }
        }
    }
}

// K2: rescore candidate 16-code groups replicating np f32 semantics:
// d = f32(f32(zsum + esum[k]) - f32(2 * f32(dot64))), argmin with
// FIRST-INDEX tie-break. 4 waves/block, wave owns pixels 4w..4w+3.
__global__ __launch_bounds__(256) void vq_phase2(const float* __restrict__ z,
                                                 const float* __restrict__ cb,
                                                 const float* __restrict__ esum32,
                                                 const unsigned short* __restrict__ gmin,
                                                 unsigned int* __restrict__ idxw) {
    __shared__ float zt[16 * 260];
    __shared__ unsigned short gm[NGRP * 17];
    __shared__ float zs[16];
    int t = threadIdx.x;
    int wave = t >> 6, lane = t & 63;
    int p0 = blockIdx.x * 16;
    int bb = p0 >> 10, inner = p0 & 1023;

    #pragma unroll
    for (int i = 0; i < 16; ++i) {
        int c = i * 16 + (t >> 4), p = t & 15;
        zt[p * 260 + c] = z[((size_t)(bb * 256 + c) << 10) + inner + p];
    }
    #pragma unroll
    for (int i = 0; i < 32; ++i) {
        int g = i * 16 + (t >> 4), p = t & 15;
        gm[g * 17 + p] = gmin[(size_t)g * N_PIX + p0 + p];
    }
    __syncthreads();
    if (t < 16) {
        const float* a = zt + t * 260;
        zs[t] = __fadd_rn(np_pw128sq(a), np_pw128sq(a + 128));  // np zsum
    }
    __syncthreads();

    #pragma unroll
    for (int pp = 0; pp < 4; ++pp) {
        int p = wave * 4 + pp;
        float lmin = 3.0e38f;
        #pragma unroll
        for (int j = 0; j < 8; ++j) lmin = fminf(lmin, bf2f(gm[(lane * 8 + j) * 17 + p]));
        #pragma unroll
        for (int m = 1; m < 64; m <<= 1) lmin = fminf(lmin, __shfl_xor(lmin, m));
        float thr = lmin + MARGIN;
        float zsp = zs[p];

        float bd = 3.0e38f; int bk = 0x7FFFFFFF;
        for (int j = 0; j < 8; ++j) {
            unsigned long long mask = __ballot(bf2f(gm[(lane * 8 + j) * 17 + p]) <= thr);
            while (mask) {
                int lb = __builtin_ctzll(mask); mask &= mask - 1;
                int g = lb * 8 + j;
                int k = g * 16 + (lane >> 2);
                const f4* cr = (const f4*)(cb + (size_t)k * EDIM) + (lane & 3);
                const f4* zr = (const f4*)(zt + p * 260) + (lane & 3);
                double a0 = 0.0, a1 = 0.0, a2 = 0.0, a3 = 0.0;
                #pragma unroll
                for (int i = 0; i < 16; ++i) {
                    f4 x = zr[i * 4], y = cr[i * 4];
                    a0 = fma((double)x[0], (double)y[0], a0);
                    a1 = fma((double)x[1], (double)y[1], a1);
                    a2 = fma((double)x[2], (double)y[2], a2);
                    a3 = fma((double)x[3], (double)y[3], a3);
                }
                double s = (a0 + a1) + (a2 + a3);
                s += __shfl_xor(s, 1);
                s += __shfl_xor(s, 2);
                float E = (float)s;                                   // einsum f32 surrogate
                float d = __fsub_rn(__fadd_rn(zsp, esum32[k]), __fmul_rn(2.0f, E));
                if (d < bd || (d == bd && k < bk)) { bd = d; bk = k; }
            }
        }
        #pragma unroll
        for (int m = 1; m < 64; m <<= 1) {
            float od = __shfl_xor(bd, m); int ok = __shfl_xor(bk, m);
            if (od < bd || (od == bd && ok < bk)) { bd = od; bk = ok; }
        }
        if (lane == 0) idxw[p0 + p] = (unsigned int)bk;
    }
}

// K3: SOLE final writer of z_q (f32 chunk0, overwrites gmin scratch) and
// indices (f32 chunk2).
__global__ __launch_bounds__(256) void vq_emit(const float* __restrict__ cb,
                                               const float* __restrict__ z,
                                               const unsigned int* __restrict__ idxw,
                                               float* __restrict__ outf,
                                               float* __restrict__ lossw) {
    __shared__ float red[4];
    int t = threadIdx.x;
    int gtid = blockIdx.x * 256 + t;
    if (gtid < N_PIX) outf[ZQ_ELEMS + 1 + gtid] = (float)(idxw[gtid] & (NE - 1));

    float acc = 0.f;
    size_t base = (size_t)blockIdx.x * 16384;
    for (int i = 0; i < 64; ++i) {
        size_t o = base + (size_t)i * 256 + t;
        int b = (int)(o >> 18);
        int c = (int)((o >> 10) & 255);
        int p = (int)(o & 1023);
        int idx = (int)(idxw[b * 1024 + p] & (NE - 1));
        float qv = cb[(size_t)idx * EDIM + c];
        outf[o] = qv;
        float d = qv - z[o];
        acc = fmaf(d, d, acc);
    }
    #pragma unroll
    for (int off = 32; off > 0; off >>= 1) acc += __shfl_down(acc, off);
    if ((t & 63) == 0) red[t >> 6] = acc;
    __syncthreads();
    if (t == 0) atomicAdd(lossw, red[0] + red[1] + red[2] + red[3]);
}

// K4: SOLE writer of loss (f32 chunk1).
__global__ void vq_finalize(const float* __restrict__ lossw, float* __restrict__ loss_out) {
    loss_out[0] = 1.25f * lossw[0] * (1.0f / 4194304.0f);
}

extern "C" void kernel_launch(void* const* d_in, const int* in_sizes, int n_in,
                              void* d_out, int out_size, void* d_ws, size_t ws_size,
                              hipStream_t stream) {
    const float* z  = (const float*)d_in[0];   // f32 [16,256,32,32]
    const float* cb = (const float*)d_in[1];   // f32 [8192,256]
    float* outf = (float*)d_out;               // f32 [z_q | loss | indices]
    // gmin scratch (512 groups x 16384 px, u16 = 16.78 MB) lives in the z_q
    // chunk of d_out between phase1 and phase2; vq_emit overwrites it.
    unsigned short* gmin = (unsigned short*)d_out;

    char* w = (char*)d_ws;
    unsigned short* cb16   = (unsigned short*)w;               //  4,194,304 B
    float*          esum32 = (float*)(w + 4194304);            //     32,768 B
    unsigned int*   idxw   = (unsigned int*)(w + 4227072);     //     65,536 B
    float*          lossw  = (float*)(w + 4292608);            //          4 B (pad to 256)
    unsigned short* z16    = (unsigned short*)(w + 4292864);   //  8,388,608 B -> 12,681,472

    if (ws_size < 4292612) return;  // diagnostic: all-zero out => ws too small
    const bool big_ws = (ws_size >= 12681472);

    hipMemsetAsync(lossw, 0, sizeof(float), stream);
    vq_prep    <<<NE / 64, 256, 0, stream>>>(cb, cb16, esum32);
    if (big_ws) {
        vq_zprep  <<<(N_PIX / 64) * (EDIM / 64), 256, 0, stream>>>(z, z16);
        vq_phase1g<<<(NE / 256) * (N_PIX / 2048), 512, 0, stream>>>(cb16, z16, gmin);
    } else {
        vq_phase1 <<<(N_PIX / 64) * 2, 512, 0, stream>>>(z, cb16, gmin);
    }
    vq_phase2  <<<N_PIX / 16, 256, 0, stream>>>(z, cb, esum32, gmin, idxw);
    vq_emit    <<<256, 256, 0, stream>>>(cb, z, idxw, outf, lossw);
    vq_finalize<<<1, 1, 0, stream>>>(lossw, outf + ZQ_ELEMS);
}

// Round 5
// 276.693 us; speedup vs baseline: 1.0201x; 1.0201x over previous
//
#include <hip/hip_runtime.h>

typedef short s8v __attribute__((ext_vector_type(8)));
typedef float f4v __attribute__((ext_vector_type(4)));
typedef float f4 __attribute__((ext_vector_type(4)));

#define N_PIX 16384
#define NE    8192
#define EDIM  256
#define ZQ_ELEMS 4194304
#define MARGIN 4.5e-4f
#define NGRP 512           // 16 codes per pruning group

__device__ __forceinline__ float bf2f(unsigned short u) {
    union { unsigned int i; float f; } c; c.i = ((unsigned int)u) << 16; return c.f;
}
__device__ __forceinline__ unsigned short f2bf(float f) {
    unsigned int u = __float_as_uint(f);
    u = (u + 0x7fffu + ((u >> 16) & 1u)) >> 16;   // RNE
    return (unsigned short)u;
}
__device__ __forceinline__ unsigned short f2bf_down(float f) {  // round toward -inf
    unsigned int u = __float_as_uint(f);
    unsigned short b = (unsigned short)(u >> 16);
    if ((u & 0xFFFFu) && (u >> 31)) b += 1;
    return b;
}

// numpy pairwise_sum over 128 squared elements (exact replication: 8
// accumulators, fixed combine tree), f32 RN ops, no FMA contraction.
__device__ __forceinline__ float np_pw128sq(const float* a) {
    float r[8];
    #pragma unroll
    for (int j = 0; j < 8; ++j) r[j] = __fmul_rn(a[j], a[j]);
    for (int i = 8; i < 128; i += 8)
        #pragma unroll
        for (int j = 0; j < 8; ++j) r[j] = __fadd_rn(r[j], __fmul_rn(a[i + j], a[i + j]));
    return __fadd_rn(__fadd_rn(__fadd_rn(r[0], r[1]), __fadd_rn(r[2], r[3])),
                     __fadd_rn(__fadd_rn(r[4], r[5]), __fadd_rn(r[6], r[7])));
}

// K0: cb16 = bf16(cb); esum32[k] = np.sum(cb[k]*cb[k]) in exact np-f32
// pairwise semantics. WS-only writes.
__global__ __launch_bounds__(256) void vq_prep(const float* __restrict__ cb,
                                               unsigned short* __restrict__ cb16,
                                               float* __restrict__ esum32) {
    int t = threadIdx.x;
    int base = blockIdx.x * 64;
    const float* src = cb + (size_t)base * EDIM;
    unsigned short* dst = cb16 + (size_t)base * EDIM;
    for (int i = 0; i < 64; ++i) dst[i * EDIM + t] = f2bf(src[i * EDIM + t]);
    if (t < 64) {
        const float* a = cb + (size_t)(base + t) * EDIM;
        esum32[base + t] = __fadd_rn(np_pw128sq(a), np_pw128sq(a + 128));
    }
}

// K0b: z16[pixel][channel] = bf16(z) -- pixel-major transpose of z so
// phase1g can stage it with clean global_load_lds. LDS-transpose tile
// 64px x 64ch; reads and writes both coalesced; f2bf identical to what
// the old phase1 applied per element (bit-identical MFMA inputs).
__global__ __launch_bounds__(256) void vq_zprep(const float* __restrict__ z,
                                                unsigned short* __restrict__ z16) {
    __shared__ unsigned short zl[64 * 66];   // 66 stride: odd bank step
    int t = threadIdx.x;
    int p0 = (blockIdx.x >> 2) * 64;         // 64 | 1024, tile stays in one image
    int c0 = (blockIdx.x & 3) * 64;
    int b = p0 >> 10, hw0 = p0 & 1023;
    const float* src = z + (((size_t)b * 256 + c0) << 10) + hw0;
    #pragma unroll
    for (int i = 0; i < 16; ++i) {
        int idx = i * 256 + t;
        int ch = idx >> 6, px = idx & 63;    // lanes sweep px: coalesced f32 read
        zl[px * 66 + ch] = f2bf(src[((size_t)ch << 10) + px]);
    }
    __syncthreads();
    #pragma unroll
    for (int i = 0; i < 16; ++i) {
        int idx = i * 256 + t;
        int px = idx >> 6, ch = idx & 63;    // lanes sweep ch: coalesced u16 write
        z16[((size_t)(p0 + px)) * 256 + c0 + ch] = zl[px * 66 + ch];
    }
}

// K1: persistent-N 256x256-tile bf16 GEMM with REGISTER-PIPELINED phases.
// Round-4 post-mortem: 8 barriers/K-tile serialized ds_read slots against
// MFMA slots (768+620 cyc ADDED per phase-pair -> 7.6k cyc/K-tile vs 2.5k
// floor). Fix: frag double-buffering in registers (A0/A1,B0/B1). Each phase
// issues the NEXT phase's 4-8 ds_reads, then runs the current 16-MFMA
// cluster; compiler emits counted lgkmcnt(4/8) so reads overlap MFMA.
// Barriers cut to 2/K-tile: (1) iter-top WAR barrier before staging buf^1
// (all waves' reads of it completed before their prior ph3 MFMA);
// (2) ph3 RAW gate: per-wave vmcnt(0) (own 8 GLL, issued 3 phases earlier
// ~2000cy cover) + barrier, then cross-buffer ph0' frag prefetch.
// Geometry/LDS/swizzle/staging/XCD mapping identical to round 4 (verified):
// 8 waves 2Mx4N, per-wave 128x64, BK=64, involution chunk-swizzle
// q^((r>>1)&3), block owns 256 codes x 2048 px (8 px-tiles, 32 K-tile its),
// grid 256 = 1 block/CU, pg = XCD. K order per acc element: kt,ksub
// ascending -> gmin bit-identical.
__global__ __launch_bounds__(512, 2) void vq_phase1g(const unsigned short* __restrict__ cb16,
                                                     const unsigned short* __restrict__ z16,
                                                     unsigned short* __restrict__ gmin) {
    __shared__ unsigned short L[2][32768];   // [buf][A 16K u16 | B 16K u16] = 128 KB
    const int t = threadIdx.x;
    const int wave = t >> 6, lane = t & 63;
    const int q = lane >> 4, r = lane & 15;
    const int wr = wave >> 2, wc = wave & 3;      // 2 M-waves x 4 N-waves
    const int cm0 = ((int)blockIdx.x >> 3) * 256; // code tile (32 of them)
    const int pg  = (int)blockIdx.x & 7;          // px-group (8): one per XCD

    // Staging: half-step = 256 rows x 32 k of one operand = 2 x 16B/thread.
    // Physical slot pc=(row,cph) holds logical chunk lc = cph ^ ((row>>1)&3).
    const int pc0 = t, pc1 = t + 512;
    const int row0 = pc0 >> 2, row1 = pc1 >> 2;
    const int lc0 = (pc0 & 3) ^ ((row0 >> 1) & 3);
    const int lc1 = (pc1 & 3) ^ ((row1 >> 1) & 3);
    const int go0 = row0 * 256 + lc0 * 8;   // u16; + kh*32 + kt*64
    const int go1 = row1 * 256 + lc1 * 8;
    const int ld0 = pc0 * 8;                // u16 within half; + kh*8192
    const int ld1 = pc1 * 8;

    const unsigned short* gA = cb16 + (size_t)cm0 * 256;
    const unsigned short* gB0 = z16 + (size_t)pg * 2048 * 256;  // px-group base

    f4v acc[8][4];
    const f4v zz = {0.f, 0.f, 0.f, 0.f};
    #pragma unroll
    for (int mi = 0; mi < 8; ++mi)
        #pragma unroll
        for (int ni = 0; ni < 4; ++ni) acc[mi][ni] = zz;

    const int cxo = (q ^ ((r >> 1) & 3)) * 8;     // swizzled chunk offset (u16)
    const int aro = (wr * 128 + r) * 32 + cxo;    // A frag base (u16, +mi*512, +ks*8192)
    const int bro = 16384 + (wc * 64 + r) * 32 + cxo; // B frag base (+ni*512, +ks*8192)

#define GLL(g, l) __builtin_amdgcn_global_load_lds( \
        (const __attribute__((address_space(1))) unsigned int*)(g), \
        (__attribute__((address_space(3))) unsigned int*)(l), 16, 0, 0)
// stage one full K-tile (A k0,k1 + B k0,k1) = 8 GLL/thread
#define STAGEKT(buf_, gk_, gBp_) do { \
        unsigned short* Lb = &L[(buf_)][0]; \
        GLL(gA + go0 + (gk_),            Lb + ld0); \
        GLL(gA + go1 + (gk_),            Lb + ld1); \
        GLL(gA + go0 + 32 + (gk_),       Lb + 8192 + ld0); \
        GLL(gA + go1 + 32 + (gk_),       Lb + 8192 + ld1); \
        GLL((gBp_) + go0 + (gk_),        Lb + 16384 + ld0); \
        GLL((gBp_) + go1 + (gk_),        Lb + 16384 + ld1); \
        GLL((gBp_) + go0 + 32 + (gk_),   Lb + 16384 + 8192 + ld0); \
        GLL((gBp_) + go1 + 32 + (gk_),   Lb + 16384 + 8192 + ld1); } while (0)
#define ARD(Lp, mi, ks) (*(const s8v*)&(Lp)[(ks) * 8192 + (mi) * 512 + aro])
#define BRD(Lp, ni, ks) (*(const s8v*)&(Lp)[(ks) * 8192 + (ni) * 512 + bro])
#define MFMA16(Aset, Bset, mo) do { \
        __builtin_amdgcn_s_setprio(1); \
        _Pragma("unroll") \
        for (int mi = 0; mi < 4; ++mi) \
            _Pragma("unroll") \
            for (int ni = 0; ni < 4; ++ni) \
                acc[(mo) + mi][ni] = __builtin_amdgcn_mfma_f32_16x16x32_bf16( \
                    Aset[mi], Bset[ni], acc[(mo) + mi][ni], 0, 0, 0); \
        __builtin_amdgcn_s_setprio(0); } while (0)

    // prologue: stage K-tile 0 -> buf0; drain; barrier; prefetch ph0 frags.
    STAGEKT(0, 0, gB0);
    asm volatile("s_waitcnt vmcnt(0)" ::: "memory");
    __builtin_amdgcn_s_barrier();
    s8v A0[4], A1[4], B0[4], B1[4];
    #pragma unroll
    for (int ni = 0; ni < 4; ++ni) B0[ni] = BRD(&L[0][0], ni, 0);
    #pragma unroll
    for (int mi = 0; mi < 4; ++mi) A0[mi] = ARD(&L[0][0], mi, 0);

    for (int it = 0; it < 32; ++it) {             // it = px*4 + kt
        const int buf = it & 1;
        const unsigned short* Lb = &L[buf][0];
        const unsigned short* Ln = &L[buf ^ 1][0];
        const int nit = it + 1;
        const bool st = nit < 32;

        __builtin_amdgcn_s_barrier();             // WAR: buf^1 readers all done
        if (st) STAGEKT(buf ^ 1, (nit & 3) * 64, gB0 + (size_t)(nit >> 2) * 65536);

        // ph0: issue A1 (mi4-7, ks0); MFMA acc[0-3] += A0*B0 (lgkm auto 4)
        #pragma unroll
        for (int mi = 0; mi < 4; ++mi) A1[mi] = ARD(Lb, 4 + mi, 0);
        __builtin_amdgcn_sched_barrier(0);
        MFMA16(A0, B0, 0);

        // ph1: issue A0 (mi0-3, ks1) + B1 (ks1); MFMA acc[4-7] += A1*B0
        #pragma unroll
        for (int mi = 0; mi < 4; ++mi) A0[mi] = ARD(Lb, mi, 1);
        #pragma unroll
        for (int ni = 0; ni < 4; ++ni) B1[ni] = BRD(Lb, ni, 1);
        __builtin_amdgcn_sched_barrier(0);
        MFMA16(A1, B0, 4);

        // ph2: issue A1 (mi4-7, ks1); MFMA acc[0-3] += A0*B1
        #pragma unroll
        for (int mi = 0; mi < 4; ++mi) A1[mi] = ARD(Lb, 4 + mi, 1);
        __builtin_amdgcn_sched_barrier(0);
        MFMA16(A0, B1, 0);

        // ph3: RAW gate (own stage landed; barrier -> ALL waves' stages
        // landed), then cross-buffer ph0' prefetch; MFMA acc[4-7] += A1*B1
        if (st) {
            asm volatile("s_waitcnt vmcnt(0)" ::: "memory");
            __builtin_amdgcn_s_barrier();
            #pragma unroll
            for (int ni = 0; ni < 4; ++ni) B0[ni] = BRD(Ln, ni, 0);
            #pragma unroll
            for (int mi = 0; mi < 4; ++mi) A0[mi] = ARD(Ln, mi, 0);
        }
        __builtin_amdgcn_sched_barrier(0);
        MFMA16(A1, B1, 4);

        // px-tile boundary: emit group-maxes, reset acc. Wave-local, uniform.
        if ((it & 3) == 3) {
            const int pn0 = pg * 2048 + (it >> 2) * 256;
            #pragma unroll
            for (int mi = 0; mi < 8; ++mi) {
                int g = cm0 / 16 + wr * 8 + mi;
                #pragma unroll
                for (int ni = 0; ni < 4; ++ni) {
                    f4v a = acc[mi][ni];
                    float mx = fmaxf(fmaxf(a[0], a[1]), fmaxf(a[2], a[3]));
                    mx = fmaxf(mx, __shfl_xor(mx, 16));
                    mx = fmaxf(mx, __shfl_xor(mx, 32));
                    if (q == 0)
                        gmin[(size_t)g * N_PIX + pn0 + wc * 64 + ni * 16 + r] =
                            f2bf_down(-2.0f * mx);
                    acc[mi][ni] = zz;
                }
            }
        }
    }
#undef MFMA16
#undef BRD
#undef ARD
#undef STAGEKT
#undef GLL
}

// K1 (fallback, unchanged): used only if workspace can't hold z16.
__global__ __launch_bounds__(512, 2) void vq_phase1(const float* __restrict__ z,
                                                    const unsigned short* __restrict__ cb16,
                                                    unsigned short* __restrict__ gmin) {
    const int t = threadIdx.x;
    const int wave = t >> 6, lane = t & 63;
    const int col = lane & 15, q = lane >> 4;
    const int mb = (blockIdx.x >> 1) * 64;
    const int chalf = blockIdx.x & 1;

    s8v Z[4][8];
    #pragma unroll
    for (int pt = 0; pt < 4; ++pt) {
        int n = mb + pt * 16 + col;
        const float* zb = z + ((size_t)(n >> 10) << 18) + (size_t)(n & 1023);
        #pragma unroll
        for (int c0 = 0; c0 < 8; ++c0) {
            s8v a;
            #pragma unroll
            for (int j = 0; j < 8; ++j) {
                int c = c0 * 32 + q * 8 + j;
                a[j] = (short)f2bf(zb[(size_t)c << 10]);
            }
            Z[pt][c0] = a;
        }
    }

    const int kbase = chalf * 4096 + wave * 512;
    for (int it = 0; it < 16; ++it) {
        int n0 = kbase + it * 32;
        const unsigned short* bb = cb16 + (size_t)(n0 + col) * EDIM + q * 8;
        f4v zz = {0.f, 0.f, 0.f, 0.f};
        f4v acc[4][2];
        #pragma unroll
        for (int pt = 0; pt < 4; ++pt) { acc[pt][0] = zz; acc[pt][1] = zz; }
        #pragma unroll
        for (int c0 = 0; c0 < 8; ++c0) {
            s8v C0 = *(const s8v*)(bb + c0 * 32);
            s8v C1 = *(const s8v*)(bb + 16 * EDIM + c0 * 32);
            #pragma unroll
            for (int pt = 0; pt < 4; ++pt) {
                acc[pt][0] = __builtin_amdgcn_mfma_f32_16x16x32_bf16(C0, Z[pt][c0], acc[pt][0], 0, 0, 0);
                acc[pt][1] = __builtin_amdgcn_mfma_f32_16x16x32_bf16(C1, Z[pt][c0], acc[pt][1], 0, 0, 0);
            }
        }
        int gbase = chalf * 256 + wave * 32 + it * 2;
        #pragma unroll
        for (int pt = 0; pt < 4; ++pt) {
            #pragma unroll
            for (int s = 0; s < 2; ++s) {
                f4v a = acc[pt][s];
                float mx = fmaxf(fmaxf(a[0], a[1]), fmaxf(a[2], a[3]));
                mx = fmaxf(mx, __shfl_xor(mx, 16));
                mx = fmaxf(mx, __shfl_xor(mx, 32));
                if (q == 0)
                    gmin[(size_t)(gbase + s) * N_PIX + mb + pt * 16 + col] =
                        f2bf_down(-2.0f * mx);
            }
        }
    }
}

// K2: rescore candidate 16-code groups replicating np f32 semantics:
// d = f32(f32(zsum + esum[k]) - f32(2 * f32(dot64))), argmin with
// FIRST-INDEX tie-break. 4 waves/block, wave owns pixels 4w..4w+3.
__global__ __launch_bounds__(256) void vq_phase2(const float* __restrict__ z,
                                                 const float* __restrict__ cb,
                                                 const float* __restrict__ esum32,
                                                 const unsigned short* __restrict__ gmin,
                                                 unsigned int* __restrict__ idxw) {
    __shared__ float zt[16 * 260];
    __shared__ unsigned short gm[NGRP * 17];
    __shared__ float zs[16];
    int t = threadIdx.x;
    int wave = t >> 6, lane = t & 63;
    int p0 = blockIdx.x * 16;
    int bb = p0 >> 10, inner = p0 & 1023;

    #pragma unroll
    for (int i = 0; i < 16; ++i) {
        int c = i * 16 + (t >> 4), p = t & 15;
        zt[p * 260 + c] = z[((size_t)(bb * 256 + c) << 10) + inner + p];
    }
    #pragma unroll
    for (int i = 0; i < 32; ++i) {
        int g = i * 16 + (t >> 4), p = t & 15;
        gm[g * 17 + p] = gmin[(size_t)g * N_PIX + p0 + p];
    }
    __syncthreads();
    if (t < 16) {
        const float* a = zt + t * 260;
        zs[t] = __fadd_rn(np_pw128sq(a), np_pw128sq(a + 128));  // np zsum
    }
    __syncthreads();

    #pragma unroll
    for (int pp = 0; pp < 4; ++pp) {
        int p = wave * 4 + pp;
        float lmin = 3.0e38f;
        #pragma unroll
        for (int j = 0; j < 8; ++j) lmin = fminf(lmin, bf2f(gm[(lane * 8 + j) * 17 + p]));
        #pragma unroll
        for (int m = 1; m < 64; m <<= 1) lmin = fminf(lmin, __shfl_xor(lmin, m));
        float thr = lmin + MARGIN;
        float zsp = zs[p];

        float bd = 3.0e38f; int bk = 0x7FFFFFFF;
        for (int j = 0; j < 8; ++j) {
            unsigned long long mask = __ballot(bf2f(gm[(lane * 8 + j) * 17 + p]) <= thr);
            while (mask) {
                int lb = __builtin_ctzll(mask); mask &= mask - 1;
                int g = lb * 8 + j;
                int k = g * 16 + (lane >> 2);
                const f4* cr = (const f4*)(cb + (size_t)k * EDIM) + (lane & 3);
                const f4* zr = (const f4*)(zt + p * 260) + (lane & 3);
                double a0 = 0.0, a1 = 0.0, a2 = 0.0, a3 = 0.0;
                #pragma unroll
                for (int i = 0; i < 16; ++i) {
                    f4 x = zr[i * 4], y = cr[i * 4];
                    a0 = fma((double)x[0], (double)y[0], a0);
                    a1 = fma((double)x[1], (double)y[1], a1);
                    a2 = fma((double)x[2], (double)y[2], a2);
                    a3 = fma((double)x[3], (double)y[3], a3);
                }
                double s = (a0 + a1) + (a2 + a3);
                s += __shfl_xor(s, 1);
                s += __shfl_xor(s, 2);
                float E = (float)s;                                   // einsum f32 surrogate
                float d = __fsub_rn(__fadd_rn(zsp, esum32[k]), __fmul_rn(2.0f, E));
                if (d < bd || (d == bd && k < bk)) { bd = d; bk = k; }
            }
        }
        #pragma unroll
        for (int m = 1; m < 64; m <<= 1) {
            float od = __shfl_xor(bd, m); int ok = __shfl_xor(bk, m);
            if (od < bd || (od == bd && ok < bk)) { bd = od; bk = ok; }
        }
        if (lane == 0) idxw[p0 + p] = (unsigned int)bk;
    }
}

// K3: SOLE final writer of z_q (f32 chunk0, overwrites gmin scratch) and
// indices (f32 chunk2).
__global__ __launch_bounds__(256) void vq_emit(const float* __restrict__ cb,
                                               const float* __restrict__ z,
                                               const unsigned int* __restrict__ idxw,
                                               float* __restrict__ outf,
                                               float* __restrict__ lossw) {
    __shared__ float red[4];
    int t = threadIdx.x;
    int gtid = blockIdx.x * 256 + t;
    if (gtid < N_PIX) outf[ZQ_ELEMS + 1 + gtid] = (float)(idxw[gtid] & (NE - 1));

    float acc = 0.f;
    size_t base = (size_t)blockIdx.x * 16384;
    for (int i = 0; i < 64; ++i) {
        size_t o = base + (size_t)i * 256 + t;
        int b = (int)(o >> 18);
        int c = (int)((o >> 10) & 255);
        int p = (int)(o & 1023);
        int idx = (int)(idxw[b * 1024 + p] & (NE - 1));
        float qv = cb[(size_t)idx * EDIM + c];
        outf[o] = qv;
        float d = qv - z[o];
        acc = fmaf(d, d, acc);
    }
    #pragma unroll
    for (int off = 32; off > 0; off >>= 1) acc += __shfl_down(acc, off);
    if ((t & 63) == 0) red[t >> 6] = acc;
    __syncthreads();
    if (t == 0) atomicAdd(lossw, red[0] + red[1] + red[2] + red[3]);
}

// K4: SOLE writer of loss (f32 chunk1).
__global__ void vq_finalize(const float* __restrict__ lossw, float* __restrict__ loss_out) {
    loss_out[0] = 1.25f * lossw[0] * (1.0f / 4194304.0f);
}

extern "C" void kernel_launch(void* const* d_in, const int* in_sizes, int n_in,
                              void* d_out, int out_size, void* d_ws, size_t ws_size,
                              hipStream_t stream) {
    const float* z  = (const float*)d_in[0];   // f32 [16,256,32,32]
    const float* cb = (const float*)d_in[1];   // f32 [8192,256]
    float* outf = (float*)d_out;               // f32 [z_q | loss | indices]
    // gmin scratch (512 groups x 16384 px, u16 = 16.78 MB) lives in the z_q
    // chunk of d_out between phase1 and phase2; vq_emit overwrites it.
    unsigned short* gmin = (unsigned short*)d_out;

    char* w = (char*)d_ws;
    unsigned short* cb16   = (unsigned short*)w;               //  4,194,304 B
    float*          esum32 = (float*)(w + 4194304);            //     32,768 B
    unsigned int*   idxw   = (unsigned int*)(w + 4227072);     //     65,536 B
    float*          lossw  = (float*)(w + 4292608);            //          4 B (pad to 256)
    unsigned short* z16    = (unsigned short*)(w + 4292864);   //  8,388,608 B -> 12,681,472

    if (ws_size < 4292612) return;  // diagnostic: all-zero out => ws too small
    const bool big_ws = (ws_size >= 12681472);

    hipMemsetAsync(lossw, 0, sizeof(float), stream);
    vq_prep    <<<NE / 64, 256, 0, stream>>>(cb, cb16, esum32);
    if (big_ws) {
        vq_zprep  <<<(N_PIX / 64) * (EDIM / 64), 256, 0, stream>>>(z, z16);
        vq_phase1g<<<(NE / 256) * (N_PIX / 2048), 512, 0, stream>>>(cb16, z16, gmin);
    } else {
        vq_phase1 <<<(N_PIX / 64) * 2, 512, 0, stream>>>(z, cb16, gmin);
    }
    vq_phase2  <<<N_PIX / 16, 256, 0, stream>>>(z, cb, esum32, gmin, idxw);
    vq_emit    <<<256, 256, 0, stream>>>(cb, z, idxw, outf, lossw);
    vq_finalize<<<1, 1, 0, stream>>>(lossw, outf + ZQ_ELEMS);
}

// Round 6
// 263.797 us; speedup vs baseline: 1.0699x; 1.0489x over previous
//
#include <hip/hip_runtime.h>

typedef short s8v __attribute__((ext_vector_type(8)));
typedef float f4v __attribute__((ext_vector_type(4)));
typedef float f4 __attribute__((ext_vector_type(4)));
typedef unsigned short u16v4 __attribute__((ext_vector_type(4)));

#define N_PIX 16384
#define NE    8192
#define EDIM  256
#define ZQ_ELEMS 4194304
#define MARGIN 4.5e-4f
#define NGRP 512           // 16 codes per pruning group

__device__ __forceinline__ float bf2f(unsigned short u) {
    union { unsigned int i; float f; } c; c.i = ((unsigned int)u) << 16; return c.f;
}
__device__ __forceinline__ unsigned short f2bf(float f) {
    unsigned int u = __float_as_uint(f);
    u = (u + 0x7fffu + ((u >> 16) & 1u)) >> 16;   // RNE
    return (unsigned short)u;
}
__device__ __forceinline__ unsigned short f2bf_down(float f) {  // round toward -inf
    unsigned int u = __float_as_uint(f);
    unsigned short b = (unsigned short)(u >> 16);
    if ((u & 0xFFFFu) && (u >> 31)) b += 1;
    return b;
}

// numpy pairwise_sum over 128 squared elements (exact replication: 8
// accumulators, fixed combine tree), f32 RN ops, no FMA contraction.
__device__ __forceinline__ float np_pw128sq(const float* a) {
    float r[8];
    #pragma unroll
    for (int j = 0; j < 8; ++j) r[j] = __fmul_rn(a[j], a[j]);
    for (int i = 8; i < 128; i += 8)
        #pragma unroll
        for (int j = 0; j < 8; ++j) r[j] = __fadd_rn(r[j], __fmul_rn(a[i + j], a[i + j]));
    return __fadd_rn(__fadd_rn(__fadd_rn(r[0], r[1]), __fadd_rn(r[2], r[3])),
                     __fadd_rn(__fadd_rn(r[4], r[5]), __fadd_rn(r[6], r[7])));
}

// gmin scratch layout (NEW): [px_chunk 1024][group 512][px-in-chunk 16] u16.
// Writers (phase1/phase1g) keep 32B-coalesced 16-lane stores; phase2 reads
// its block's slice as ONE contiguous 16 KB run (was 512 strided 32B reads).

// K0: cb16 = bf16(cb); esum32[k] = np.sum(cb[k]*cb[k]) in exact np-f32
// pairwise semantics. Vectorized: f4 loads + short4 stores, 256 blocks.
__global__ __launch_bounds__(256) void vq_prep(const float* __restrict__ cb,
                                               unsigned short* __restrict__ cb16,
                                               float* __restrict__ esum32) {
    int t = threadIdx.x;
    int base = blockIdx.x * 32;                       // 256 blocks x 32 rows
    const float* src = cb + (size_t)base * EDIM;
    unsigned short* dst = cb16 + (size_t)base * EDIM;
    #pragma unroll
    for (int i = 0; i < 8; ++i) {
        int e0 = (i * 256 + t) * 4;                   // 32*256 channels total
        f4 v = *(const f4*)(src + e0);
        u16v4 o;
        o.x = f2bf(v[0]); o.y = f2bf(v[1]); o.z = f2bf(v[2]); o.w = f2bf(v[3]);
        *(u16v4*)(dst + e0) = o;
    }
    if (t < 32) {
        const float* a = cb + (size_t)(base + t) * EDIM;
        esum32[base + t] = __fadd_rn(np_pw128sq(a), np_pw128sq(a + 128));
    }
}

// K0b: z16[pixel][channel] = bf16(z) -- pixel-major transpose of z so
// phase1g can stage it with clean global_load_lds. Unchanged (verified).
__global__ __launch_bounds__(256) void vq_zprep(const float* __restrict__ z,
                                                unsigned short* __restrict__ z16) {
    __shared__ unsigned short zl[64 * 66];   // 66 stride: odd bank step
    int t = threadIdx.x;
    int p0 = (blockIdx.x >> 2) * 64;         // 64 | 1024, tile stays in one image
    int c0 = (blockIdx.x & 3) * 64;
    int b = p0 >> 10, hw0 = p0 & 1023;
    const float* src = z + (((size_t)b * 256 + c0) << 10) + hw0;
    #pragma unroll
    for (int i = 0; i < 16; ++i) {
        int idx = i * 256 + t;
        int ch = idx >> 6, px = idx & 63;    // lanes sweep px: coalesced f32 read
        zl[px * 66 + ch] = f2bf(src[((size_t)ch << 10) + px]);
    }
    __syncthreads();
    #pragma unroll
    for (int i = 0; i < 16; ++i) {
        int idx = i * 256 + t;
        int px = idx >> 6, ch = idx & 63;    // lanes sweep ch: coalesced u16 write
        z16[((size_t)(p0 + px)) * 256 + c0 + ch] = zl[px * 66 + ch];
    }
}

// K1: persistent-N 256x256-tile bf16 GEMM with register-pipelined phases.
// UNCHANGED from round 5 (best measured, 96.6us) except the gmin store
// addressing for the new [px_chunk][g][16] layout. K order per acc element:
// kt,ksub ascending -> gmin values bit-identical.
__global__ __launch_bounds__(512, 2) void vq_phase1g(const unsigned short* __restrict__ cb16,
                                                     const unsigned short* __restrict__ z16,
                                                     unsigned short* __restrict__ gmin) {
    __shared__ unsigned short L[2][32768];   // [buf][A 16K u16 | B 16K u16] = 128 KB
    const int t = threadIdx.x;
    const int wave = t >> 6, lane = t & 63;
    const int q = lane >> 4, r = lane & 15;
    const int wr = wave >> 2, wc = wave & 3;      // 2 M-waves x 4 N-waves
    const int cm0 = ((int)blockIdx.x >> 3) * 256; // code tile (32 of them)
    const int pg  = (int)blockIdx.x & 7;          // px-group (8): one per XCD

    const int pc0 = t, pc1 = t + 512;
    const int row0 = pc0 >> 2, row1 = pc1 >> 2;
    const int lc0 = (pc0 & 3) ^ ((row0 >> 1) & 3);
    const int lc1 = (pc1 & 3) ^ ((row1 >> 1) & 3);
    const int go0 = row0 * 256 + lc0 * 8;   // u16; + kh*32 + kt*64
    const int go1 = row1 * 256 + lc1 * 8;
    const int ld0 = pc0 * 8;                // u16 within half; + kh*8192
    const int ld1 = pc1 * 8;

    const unsigned short* gA = cb16 + (size_t)cm0 * 256;
    const unsigned short* gB0 = z16 + (size_t)pg * 2048 * 256;  // px-group base

    f4v acc[8][4];
    const f4v zz = {0.f, 0.f, 0.f, 0.f};
    #pragma unroll
    for (int mi = 0; mi < 8; ++mi)
        #pragma unroll
        for (int ni = 0; ni < 4; ++ni) acc[mi][ni] = zz;

    const int cxo = (q ^ ((r >> 1) & 3)) * 8;     // swizzled chunk offset (u16)
    const int aro = (wr * 128 + r) * 32 + cxo;    // A frag base (+mi*512, +ks*8192)
    const int bro = 16384 + (wc * 64 + r) * 32 + cxo; // B frag base (+ni*512, +ks*8192)

#define GLL(g, l) __builtin_amdgcn_global_load_lds( \
        (const __attribute__((address_space(1))) unsigned int*)(g), \
        (__attribute__((address_space(3))) unsigned int*)(l), 16, 0, 0)
#define STAGEKT(buf_, gk_, gBp_) do { \
        unsigned short* Lb = &L[(buf_)][0]; \
        GLL(gA + go0 + (gk_),            Lb + ld0); \
        GLL(gA + go1 + (gk_),            Lb + ld1); \
        GLL(gA + go0 + 32 + (gk_),       Lb + 8192 + ld0); \
        GLL(gA + go1 + 32 + (gk_),       Lb + 8192 + ld1); \
        GLL((gBp_) + go0 + (gk_),        Lb + 16384 + ld0); \
        GLL((gBp_) + go1 + (gk_),        Lb + 16384 + ld1); \
        GLL((gBp_) + go0 + 32 + (gk_),   Lb + 16384 + 8192 + ld0); \
        GLL((gBp_) + go1 + 32 + (gk_),   Lb + 16384 + 8192 + ld1); } while (0)
#define ARD(Lp, mi, ks) (*(const s8v*)&(Lp)[(ks) * 8192 + (mi) * 512 + aro])
#define BRD(Lp, ni, ks) (*(const s8v*)&(Lp)[(ks) * 8192 + (ni) * 512 + bro])
#define MFMA16(Aset, Bset, mo) do { \
        __builtin_amdgcn_s_setprio(1); \
        _Pragma("unroll") \
        for (int mi = 0; mi < 4; ++mi) \
            _Pragma("unroll") \
            for (int ni = 0; ni < 4; ++ni) \
                acc[(mo) + mi][ni] = __builtin_amdgcn_mfma_f32_16x16x32_bf16( \
                    Aset[mi], Bset[ni], acc[(mo) + mi][ni], 0, 0, 0); \
        __builtin_amdgcn_s_setprio(0); } while (0)

    STAGEKT(0, 0, gB0);
    asm volatile("s_waitcnt vmcnt(0)" ::: "memory");
    __builtin_amdgcn_s_barrier();
    s8v A0[4], A1[4], B0[4], B1[4];
    #pragma unroll
    for (int ni = 0; ni < 4; ++ni) B0[ni] = BRD(&L[0][0], ni, 0);
    #pragma unroll
    for (int mi = 0; mi < 4; ++mi) A0[mi] = ARD(&L[0][0], mi, 0);

    for (int it = 0; it < 32; ++it) {             // it = px*4 + kt
        const int buf = it & 1;
        const unsigned short* Lb = &L[buf][0];
        const unsigned short* Ln = &L[buf ^ 1][0];
        const int nit = it + 1;
        const bool st = nit < 32;

        __builtin_amdgcn_s_barrier();             // WAR: buf^1 readers all done
        if (st) STAGEKT(buf ^ 1, (nit & 3) * 64, gB0 + (size_t)(nit >> 2) * 65536);

        #pragma unroll
        for (int mi = 0; mi < 4; ++mi) A1[mi] = ARD(Lb, 4 + mi, 0);
        __builtin_amdgcn_sched_barrier(0);
        MFMA16(A0, B0, 0);

        #pragma unroll
        for (int mi = 0; mi < 4; ++mi) A0[mi] = ARD(Lb, mi, 1);
        #pragma unroll
        for (int ni = 0; ni < 4; ++ni) B1[ni] = BRD(Lb, ni, 1);
        __builtin_amdgcn_sched_barrier(0);
        MFMA16(A1, B0, 4);

        #pragma unroll
        for (int mi = 0; mi < 4; ++mi) A1[mi] = ARD(Lb, 4 + mi, 1);
        __builtin_amdgcn_sched_barrier(0);
        MFMA16(A0, B1, 0);

        if (st) {
            asm volatile("s_waitcnt vmcnt(0)" ::: "memory");
            __builtin_amdgcn_s_barrier();
            #pragma unroll
            for (int ni = 0; ni < 4; ++ni) B0[ni] = BRD(Ln, ni, 0);
            #pragma unroll
            for (int mi = 0; mi < 4; ++mi) A0[mi] = ARD(Ln, mi, 0);
        }
        __builtin_amdgcn_sched_barrier(0);
        MFMA16(A1, B1, 4);

        // px-tile boundary: emit group-maxes (NEW gmin layout), reset acc.
        if ((it & 3) == 3) {
            const int pn0 = pg * 2048 + (it >> 2) * 256;
            #pragma unroll
            for (int mi = 0; mi < 8; ++mi) {
                int g = cm0 / 16 + wr * 8 + mi;
                #pragma unroll
                for (int ni = 0; ni < 4; ++ni) {
                    f4v a = acc[mi][ni];
                    float mx = fmaxf(fmaxf(a[0], a[1]), fmaxf(a[2], a[3]));
                    mx = fmaxf(mx, __shfl_xor(mx, 16));
                    mx = fmaxf(mx, __shfl_xor(mx, 32));
                    if (q == 0) {
                        int pxc = (pn0 + wc * 64 + ni * 16) >> 4;
                        gmin[(size_t)pxc * 8192 + g * 16 + r] = f2bf_down(-2.0f * mx);
                    }
                    acc[mi][ni] = zz;
                }
            }
        }
    }
#undef MFMA16
#undef BRD
#undef ARD
#undef STAGEKT
#undef GLL
}

// K1 (fallback): used only if workspace can't hold z16. Store updated to
// the new gmin layout; values unchanged.
__global__ __launch_bounds__(512, 2) void vq_phase1(const float* __restrict__ z,
                                                    const unsigned short* __restrict__ cb16,
                                                    unsigned short* __restrict__ gmin) {
    const int t = threadIdx.x;
    const int wave = t >> 6, lane = t & 63;
    const int col = lane & 15, q = lane >> 4;
    const int mb = (blockIdx.x >> 1) * 64;
    const int chalf = blockIdx.x & 1;

    s8v Z[4][8];
    #pragma unroll
    for (int pt = 0; pt < 4; ++pt) {
        int n = mb + pt * 16 + col;
        const float* zb = z + ((size_t)(n >> 10) << 18) + (size_t)(n & 1023);
        #pragma unroll
        for (int c0 = 0; c0 < 8; ++c0) {
            s8v a;
            #pragma unroll
            for (int j = 0; j < 8; ++j) {
                int c = c0 * 32 + q * 8 + j;
                a[j] = (short)f2bf(zb[(size_t)c << 10]);
            }
            Z[pt][c0] = a;
        }
    }

    const int kbase = chalf * 4096 + wave * 512;
    for (int it = 0; it < 16; ++it) {
        int n0 = kbase + it * 32;
        const unsigned short* bb = cb16 + (size_t)(n0 + col) * EDIM + q * 8;
        f4v zz = {0.f, 0.f, 0.f, 0.f};
        f4v acc[4][2];
        #pragma unroll
        for (int pt = 0; pt < 4; ++pt) { acc[pt][0] = zz; acc[pt][1] = zz; }
        #pragma unroll
        for (int c0 = 0; c0 < 8; ++c0) {
            s8v C0 = *(const s8v*)(bb + c0 * 32);
            s8v C1 = *(const s8v*)(bb + 16 * EDIM + c0 * 32);
            #pragma unroll
            for (int pt = 0; pt < 4; ++pt) {
                acc[pt][0] = __builtin_amdgcn_mfma_f32_16x16x32_bf16(C0, Z[pt][c0], acc[pt][0], 0, 0, 0);
                acc[pt][1] = __builtin_amdgcn_mfma_f32_16x16x32_bf16(C1, Z[pt][c0], acc[pt][1], 0, 0, 0);
            }
        }
        int gbase = chalf * 256 + wave * 32 + it * 2;
        #pragma unroll
        for (int pt = 0; pt < 4; ++pt) {
            #pragma unroll
            for (int s = 0; s < 2; ++s) {
                f4v a = acc[pt][s];
                float mx = fmaxf(fmaxf(a[0], a[1]), fmaxf(a[2], a[3]));
                mx = fmaxf(mx, __shfl_xor(mx, 16));
                mx = fmaxf(mx, __shfl_xor(mx, 32));
                if (q == 0)
                    gmin[(size_t)((mb >> 4) + pt) * 8192 + (gbase + s) * 16 + col] =
                        f2bf_down(-2.0f * mx);
            }
        }
    }
}

// K2: rescore candidate 16-code groups replicating np f32 semantics.
// Same numerics/tie-break as before; ONLY the gmin staging changed to the
// contiguous layout (one 16 KB linear read, vectorized b128).
__global__ __launch_bounds__(256) void vq_phase2(const float* __restrict__ z,
                                                 const float* __restrict__ cb,
                                                 const float* __restrict__ esum32,
                                                 const unsigned short* __restrict__ gmin,
                                                 unsigned int* __restrict__ idxw) {
    __shared__ float zt[16 * 260];
    __shared__ unsigned short gm[NGRP * 17];
    __shared__ float zs[16];
    int t = threadIdx.x;
    int wave = t >> 6, lane = t & 63;
    int p0 = blockIdx.x * 16;
    int bb = p0 >> 10, inner = p0 & 1023;

    #pragma unroll
    for (int i = 0; i < 16; ++i) {
        int c = i * 16 + (t >> 4), p = t & 15;
        zt[p * 260 + c] = z[((size_t)(bb * 256 + c) << 10) + inner + p];
    }
    // gmin slice for this px-chunk: contiguous 8192 u16 = 16 KB.
    const unsigned short* gsrc = gmin + (size_t)blockIdx.x * 8192;
    #pragma unroll
    for (int j = 0; j < 4; ++j) {
        int li = (j * 256 + t) * 8;              // 8 u16 per thread
        s8v v = *(const s8v*)(gsrc + li);
        int g = li >> 4, ph = li & 15;           // ph in {0,8}
        #pragma unroll
        for (int e = 0; e < 8; ++e) gm[g * 17 + ph + e] = (unsigned short)v[e];
    }
    __syncthreads();
    if (t < 16) {
        const float* a = zt + t * 260;
        zs[t] = __fadd_rn(np_pw128sq(a), np_pw128sq(a + 128));  // np zsum
    }
    __syncthreads();

    #pragma unroll
    for (int pp = 0; pp < 4; ++pp) {
        int p = wave * 4 + pp;
        float lmin = 3.0e38f;
        #pragma unroll
        for (int j = 0; j < 8; ++j) lmin = fminf(lmin, bf2f(gm[(lane * 8 + j) * 17 + p]));
        #pragma unroll
        for (int m = 1; m < 64; m <<= 1) lmin = fminf(lmin, __shfl_xor(lmin, m));
        float thr = lmin + MARGIN;
        float zsp = zs[p];

        float bd = 3.0e38f; int bk = 0x7FFFFFFF;
        for (int j = 0; j < 8; ++j) {
            unsigned long long mask = __ballot(bf2f(gm[(lane * 8 + j) * 17 + p]) <= thr);
            while (mask) {
                int lb = __builtin_ctzll(mask); mask &= mask - 1;
                int g = lb * 8 + j;
                int k = g * 16 + (lane >> 2);
                const f4* cr = (const f4*)(cb + (size_t)k * EDIM) + (lane & 3);
                const f4* zr = (const f4*)(zt + p * 260) + (lane & 3);
                double a0 = 0.0, a1 = 0.0, a2 = 0.0, a3 = 0.0;
                #pragma unroll
                for (int i = 0; i < 16; ++i) {
                    f4 x = zr[i * 4], y = cr[i * 4];
                    a0 = fma((double)x[0], (double)y[0], a0);
                    a1 = fma((double)x[1], (double)y[1], a1);
                    a2 = fma((double)x[2], (double)y[2], a2);
                    a3 = fma((double)x[3], (double)y[3], a3);
                }
                double s = (a0 + a1) + (a2 + a3);
                s += __shfl_xor(s, 1);
                s += __shfl_xor(s, 2);
                float E = (float)s;                                   // einsum f32 surrogate
                float d = __fsub_rn(__fadd_rn(zsp, esum32[k]), __fmul_rn(2.0f, E));
                if (d < bd || (d == bd && k < bk)) { bd = d; bk = k; }
            }
        }
        #pragma unroll
        for (int m = 1; m < 64; m <<= 1) {
            float od = __shfl_xor(bd, m); int ok = __shfl_xor(bk, m);
            if (od < bd || (od == bd && ok < bk)) { bd = od; bk = ok; }
        }
        if (lane == 0) idxw[p0 + p] = (unsigned int)bk;
    }
}

// K3: SOLE final writer of z_q (f32 chunk0, overwrites gmin scratch) and
// indices (f32 chunk2). NEW: the cb gather is staged through LDS -- each
// block pre-copies cb[idx[p]][c0..c0+16) per pixel with coalesced 64B f4
// reads (was 16 separate 4B line-pulling gathers per pixel = 16x line
// overfetch). Main loop keeps the EXACT per-thread element assignment and
// FMA order of the old kernel -> loss and z_q bit-identical.
__global__ __launch_bounds__(256) void vq_emit(const float* __restrict__ cb,
                                               const float* __restrict__ z,
                                               const unsigned int* __restrict__ idxw,
                                               float* __restrict__ outf,
                                               float* __restrict__ lossw) {
    __shared__ float qrow[1024 * 17];        // [p][16ch] pad 17: 2-way banks
    __shared__ unsigned int lidx[1024];
    __shared__ float red[4];
    int t = threadIdx.x;
    int gtid = blockIdx.x * 256 + t;
    if (gtid < N_PIX) outf[ZQ_ELEMS + 1 + gtid] = (float)(idxw[gtid] & (NE - 1));

    int b = blockIdx.x >> 4;                 // image
    int c0 = (blockIdx.x & 15) * 16;         // channel chunk

    #pragma unroll
    for (int j = 0; j < 4; ++j)
        lidx[j * 256 + t] = idxw[b * 1024 + j * 256 + t] & (NE - 1);
    __syncthreads();
    // stage: 4 threads per pixel, each one f4 (quad covers 64B contiguous)
    #pragma unroll
    for (int j = 0; j < 16; ++j) {
        int p = j * 64 + (t >> 2);
        f4 v = *(const f4*)(cb + (size_t)lidx[p] * EDIM + c0 + (t & 3) * 4);
        #pragma unroll
        for (int e = 0; e < 4; ++e) qrow[p * 17 + (t & 3) * 4 + e] = v[e];
    }
    __syncthreads();

    float acc = 0.f;
    size_t base = (size_t)blockIdx.x * 16384;
    for (int i = 0; i < 64; ++i) {
        size_t o = base + (size_t)i * 256 + t;
        int c = (int)((o >> 10) & 255);
        int p = (int)(o & 1023);
        float qv = qrow[p * 17 + (c - c0)];
        outf[o] = qv;
        float d = qv - z[o];
        acc = fmaf(d, d, acc);
    }
    #pragma unroll
    for (int off = 32; off > 0; off >>= 1) acc += __shfl_down(acc, off);
    if ((t & 63) == 0) red[t >> 6] = acc;
    __syncthreads();
    if (t == 0) atomicAdd(lossw, red[0] + red[1] + red[2] + red[3]);
}

// K4: SOLE writer of loss (f32 chunk1).
__global__ void vq_finalize(const float* __restrict__ lossw, float* __restrict__ loss_out) {
    loss_out[0] = 1.25f * lossw[0] * (1.0f / 4194304.0f);
}

extern "C" void kernel_launch(void* const* d_in, const int* in_sizes, int n_in,
                              void* d_out, int out_size, void* d_ws, size_t ws_size,
                              hipStream_t stream) {
    const float* z  = (const float*)d_in[0];   // f32 [16,256,32,32]
    const float* cb = (const float*)d_in[1];   // f32 [8192,256]
    float* outf = (float*)d_out;               // f32 [z_q | loss | indices]
    // gmin scratch (1024 chunks x 512 g x 16 px, u16 = 16.78 MB) lives in the
    // z_q chunk of d_out between phase1 and phase2; vq_emit overwrites it.
    unsigned short* gmin = (unsigned short*)d_out;

    char* w = (char*)d_ws;
    unsigned short* cb16   = (unsigned short*)w;               //  4,194,304 B
    float*          esum32 = (float*)(w + 4194304);            //     32,768 B
    unsigned int*   idxw   = (unsigned int*)(w + 4227072);     //     65,536 B
    float*          lossw  = (float*)(w + 4292608);            //          4 B (pad to 256)
    unsigned short* z16    = (unsigned short*)(w + 4292864);   //  8,388,608 B -> 12,681,472

    if (ws_size < 4292612) return;  // diagnostic: all-zero out => ws too small
    const bool big_ws = (ws_size >= 12681472);

    hipMemsetAsync(lossw, 0, sizeof(float), stream);
    vq_prep    <<<NE / 32, 256, 0, stream>>>(cb, cb16, esum32);
    if (big_ws) {
        vq_zprep  <<<(N_PIX / 64) * (EDIM / 64), 256, 0, stream>>>(z, z16);
        vq_phase1g<<<(NE / 256) * (N_PIX / 2048), 512, 0, stream>>>(cb16, z16, gmin);
    } else {
        vq_phase1 <<<(N_PIX / 64) * 2, 512, 0, stream>>>(z, cb16, gmin);
    }
    vq_phase2  <<<N_PIX / 16, 256, 0, stream>>>(z, cb, esum32, gmin, idxw);
    vq_emit    <<<256, 256, 0, stream>>>(cb, z, idxw, outf, lossw);
    vq_finalize<<<1, 1, 0, stream>>>(lossw, outf + ZQ_ELEMS);
}